// Round 1
// 504.465 us; speedup vs baseline: 1.0038x; 1.0038x over previous
//
#include <hip/hip_runtime.h>
#include <cstdint>
#include <cstddef>

// Problem constants
#define BT     32768   // batch (titles)
#define NW     30      // words per title
#define VOCAB  32000
#define WD     300     // word dim
#define CH     400     // conv channels
#define AD     200     // attention dim

// Padded bf16 layouts
#define EMB_LD   320   // emb_bf16 [VOCAB][320]  (300 + pad)
#define E3_LD    640   // E3 bf16 [VOCAB+1][640] (600 + pad); row ZROW unused now
#define ZROW     32000
#define U_LD     928   // U bf16 [BT][928]       (900 + pad)
#define WCT_ROWS 512   // WcT bf16 [512][928]    (400 + pad rows)
#define EXPA_LD  32    // expa [BT][32]          (30 + pad)

#define TWO_LOG2E 2.8853900817779268f   // 2*log2(e): E3 holds 2s*log2e -> exp2 direct

typedef __attribute__((ext_vector_type(8))) short bf16x8;
typedef __attribute__((ext_vector_type(4))) float f32x4;

__device__ __forceinline__ float blo(unsigned int u) {
  union { unsigned int i; float f; } x; x.i = u << 16; return x.f;
}
__device__ __forceinline__ float bhi(unsigned int u) {
  union { unsigned int i; float f; } x; x.i = u & 0xffff0000u; return x.f;
}
__device__ __forceinline__ unsigned short f2bf(float f) {
  union { float f; unsigned int i; } x; x.f = f;
  unsigned int r = x.i + 0x7FFFu + ((x.i >> 16) & 1u);   // RNE
  return (unsigned short)(r >> 16);
}
__device__ __forceinline__ unsigned int pack2bf(float a, float b) {
  return (unsigned int)f2bf(a) | ((unsigned int)f2bf(b) << 16);
}
__device__ __forceinline__ float fexp2(float x) {
#if __has_builtin(__builtin_amdgcn_exp2f)
  return __builtin_amdgcn_exp2f(x);
#else
  float r; asm volatile("v_exp_f32 %0, %1" : "=v"(r) : "v"(x)); return r;
#endif
}

// ---------------------------------------------------------------------------
// Prep: Mt[i][k*200+d] = 2*log2e * sum_c conv_w[c,i,k]*v[c,d]
// E3 then holds 2s*log2e, so scores use q*tanh(s) = q - 2q/(exp2(E3sum)+1)
// with NO per-element multiply before v_exp_f32.
//       bias2[d] = 2*log2e * (sum_c conv_b[c]*v[c,d] + vb[d])
//       q2s[d] = -2*q[d];  qsum[0] = sum_d q[d]
// ---------------------------------------------------------------------------
__global__ void prep_Mt_bias(const float* __restrict__ conv_w,
                             const float* __restrict__ conv_b,
                             const float* __restrict__ v,
                             const float* __restrict__ vb,
                             const float* __restrict__ q,
                             float* __restrict__ Mt,
                             float* __restrict__ bias2,
                             float* __restrict__ q2s,
                             float* __restrict__ qsum) {
  int blk = blockIdx.x;      // 0..899 -> Mt, 900 -> bias2, 901 -> q2s/qsum
  int d = threadIdx.x;       // 0..199
  if (blk < 900) {
    int i = blk / 3, k = blk % 3;
    float acc = 0.f;
    #pragma unroll 4
    for (int c = 0; c < CH; ++c)
      acc += conv_w[(c * WD + i) * 3 + k] * v[c * AD + d];
    Mt[i * 600 + k * AD + d] = TWO_LOG2E * acc;
  } else if (blk == 900) {
    float acc = vb[d];
    #pragma unroll 4
    for (int c = 0; c < CH; ++c)
      acc += conv_b[c] * v[c * AD + d];
    bias2[d] = TWO_LOG2E * acc;
  } else {
    q2s[d] = -2.0f * q[d];
    if (d == 0) {
      float s = 0.f;
      for (int i = 0; i < AD; ++i) s += q[i];
      qsum[0] = s;
    }
  }
}

// MtT[n][i] = bf16(Mt[i][n]) for n<600,i<300 else 0.  [E3_LD][EMB_LD]
__global__ void conv_MtT(const float* __restrict__ Mt, unsigned short* __restrict__ MtT) {
  int n = blockIdx.x;    // 640
  int i = threadIdx.x;   // 320
  float val = (n < 600 && i < WD) ? Mt[i * 600 + n] : 0.f;
  MtT[n * EMB_LD + i] = f2bf(val);
}

// WcT[c][kk] = bf16(conv_w[c, i, k]), kk = k*300+i; zero-padded. [512][928]
__global__ void prep_WcT(const float* __restrict__ conv_w, unsigned short* __restrict__ WcT) {
  int c = blockIdx.x;    // 512
  for (int kk = threadIdx.x; kk < U_LD; kk += 256) {
    float val = 0.f;
    if (c < CH && kk < 900) {
      int k = kk / WD, i = kk - k * WD;
      val = conv_w[(c * WD + i) * 3 + k];
    }
    WcT[(size_t)c * U_LD + kk] = f2bf(val);
  }
}

// emb -> bf16, zero-padded cols. [VOCAB][320]
__global__ void prep_emb_bf16(const float* __restrict__ emb, unsigned short* __restrict__ embb) {
  int idx = blockIdx.x * 256 + threadIdx.x;
  if (idx >= VOCAB * EMB_LD) return;
  int r = idx / EMB_LD, c = idx - r * EMB_LD;
  embb[idx] = (c < WD) ? f2bf(emb[(size_t)r * WD + c]) : (unsigned short)0;
}

// ---------------------------------------------------------------------------
// bf16 MFMA GEMM: C[M,N] = A[M,K] @ Bt[N,K]^T. 128x128 tile, K-step 32.
// OUT_BF16: store bf16, optional e3bias added to cols [200,400).
// else: fp32 store with col<N guard + rank-1 bias_m[r]*bias_n[c].
// ---------------------------------------------------------------------------
template<bool OUT_BF16>
__global__ __launch_bounds__(256) void gemm_mfma(
    const unsigned short* __restrict__ A, int lda,
    const unsigned short* __restrict__ Bt, int ldb,
    void* __restrict__ Cp, int ldc, int N, int K,
    const float* __restrict__ bias_m, const float* __restrict__ bias_n,
    const float* __restrict__ e3bias) {
  __shared__ unsigned short As[128][40];   // +8 pad
  __shared__ unsigned short Bs[128][40];
  int tid = threadIdx.x;
  int lane = tid & 63, wave = tid >> 6;
  int row0 = blockIdx.y * 128, col0 = blockIdx.x * 128;
  int wm = (wave & 1) * 64, wn = (wave >> 1) * 64;
  int lr = lane & 15, quad = lane >> 4;

  f32x4 acc[4][4];
  #pragma unroll
  for (int i = 0; i < 4; ++i)
    #pragma unroll
    for (int j = 0; j < 4; ++j) acc[i][j] = (f32x4){0.f, 0.f, 0.f, 0.f};

  int r0 = tid >> 2, ko0 = (tid & 3) * 8;
  int r1 = (tid + 256) >> 2, ko1 = ((tid + 256) & 3) * 8;

  for (int k0 = 0; k0 < K; k0 += 32) {
    float4 av0 = *(const float4*)(A + (size_t)(row0 + r0) * lda + k0 + ko0);
    float4 av1 = *(const float4*)(A + (size_t)(row0 + r1) * lda + k0 + ko1);
    float4 bv0 = *(const float4*)(Bt + (size_t)(col0 + r0) * ldb + k0 + ko0);
    float4 bv1 = *(const float4*)(Bt + (size_t)(col0 + r1) * ldb + k0 + ko1);
    __syncthreads();
    *(float4*)&As[r0][ko0] = av0;
    *(float4*)&As[r1][ko1] = av1;
    *(float4*)&Bs[r0][ko0] = bv0;
    *(float4*)&Bs[r1][ko1] = bv1;
    __syncthreads();

    bf16x8 af[4], bfr[4];
    #pragma unroll
    for (int mi = 0; mi < 4; ++mi)
      af[mi] = *(const bf16x8*)&As[wm + mi * 16 + lr][quad * 8];
    #pragma unroll
    for (int ni = 0; ni < 4; ++ni)
      bfr[ni] = *(const bf16x8*)&Bs[wn + ni * 16 + lr][quad * 8];
    #pragma unroll
    for (int mi = 0; mi < 4; ++mi)
      #pragma unroll
      for (int ni = 0; ni < 4; ++ni)
        acc[mi][ni] = __builtin_amdgcn_mfma_f32_16x16x32_bf16(
            af[mi], bfr[ni], acc[mi][ni], 0, 0, 0);
  }

  // Epilogue. C/D layout: col = lane&15, row = quad*4 + reg.
  if (OUT_BF16) {
    unsigned short* C = (unsigned short*)Cp;
    #pragma unroll
    for (int mi = 0; mi < 4; ++mi)
      #pragma unroll
      for (int ni = 0; ni < 4; ++ni) {
        int c = col0 + wn + ni * 16 + lr;
        float cb = (e3bias && c >= 200 && c < 400) ? e3bias[c - 200] : 0.f;
        #pragma unroll
        for (int reg = 0; reg < 4; ++reg) {
          int r = row0 + wm + mi * 16 + quad * 4 + reg;
          C[(size_t)r * ldc + c] = f2bf(acc[mi][ni][reg] + cb);
        }
      }
  } else {
    float* C = (float*)Cp;
    #pragma unroll
    for (int mi = 0; mi < 4; ++mi)
      #pragma unroll
      for (int ni = 0; ni < 4; ++ni) {
        int c = col0 + wn + ni * 16 + lr;
        if (c < N) {
          float bn = bias_n[c];
          #pragma unroll
          for (int reg = 0; reg < 4; ++reg) {
            int r = row0 + wm + mi * 16 + quad * 4 + reg;
            C[(size_t)r * ldc + c] = acc[mi][ni][reg] + bias_m[r] * bn;
          }
        }
      }
  }
}

// ---------------------------------------------------------------------------
// Scores, TITLE-per-wave, ROLLING-WINDOW over tokens + distance-1 prefetch.
// s[n] = seg0(tok[n-1]) + seg1(tok[n]) + seg2(tok[n+1]), segments of E3 row.
// Iteration m loads ALL THREE segments of row tok[m] (one scalar base, imm
// offsets 0/400/800B), distributes them to the 3-deep partial-sum window,
// and finishes word n=m-1 (sigmoid+reduce) -- so compute of iter m overlaps
// the prefetched loads for iter m+1. E3 holds 2s*log2e -> bare v_exp_f32.
// score = Qsum + sum_d q2[d]/(exp2(E3sum_d)+1), q2 = -2q.
// ---------------------------------------------------------------------------
__global__ __launch_bounds__(256) void scores_kernel(
    const int* __restrict__ tok, const unsigned short* __restrict__ E3,
    const float* __restrict__ q2s, const float* __restrict__ qsum,
    float* __restrict__ expa) {
  __shared__ float qs[AD];
  int tid = threadIdx.x;
  if (tid < AD) qs[tid] = q2s[tid];
  __syncthreads();
  int wave = tid >> 6, lane = tid & 63;
  int b = blockIdx.x * 4 + wave;
  int tk = tok[b * NW + ((lane < NW) ? lane : 0)];
  int d0 = (lane < 50) ? lane * 4 : 0;
  float4 qv = make_float4(0.f, 0.f, 0.f, 0.f);
  if (lane < 50) qv = *(const float4*)&qs[d0];   // lanes >=50 contribute 0
  float Qsum = qsum[0];
  float myscore = 0.f;

  // Prefetch row tok[0]: three 8B segment loads off one base.
  int t0r = __shfl(tk, 0, 64);
  const unsigned short* r0p = E3 + (size_t)(unsigned)t0r * E3_LD + d0;
  uint2 a0 = *(const uint2*)(r0p);          // seg0 -> s[1]
  uint2 a1 = *(const uint2*)(r0p + 200);    // seg1 -> s[0]
  uint2 a2 = *(const uint2*)(r0p + 400);    // seg2 -> s[-1] (dropped)

  // Window partials (4 components each).
  float P0 = 0.f, P1 = 0.f, P2 = 0.f, P3 = 0.f;  // s[m-1] partial
  float Q0 = 0.f, Q1 = 0.f, Q2 = 0.f, Q3 = 0.f;  // s[m]   partial (seg0(tok[-1])=0)

  #pragma unroll
  for (int m = 0; m < NW; ++m) {
    uint2 u0 = a0, u1 = a1, u2 = a2;
    if (m + 1 < NW) {   // prefetch next token's row (independent of below)
      int tn = __shfl(tk, m + 1, 64);
      const unsigned short* rp = E3 + (size_t)(unsigned)tn * E3_LD + d0;
      a0 = *(const uint2*)(rp);
      a1 = *(const uint2*)(rp + 200);
      a2 = *(const uint2*)(rp + 400);
    }
    if (m > 0) {
      // complete s[m-1] with seg2 of current row; sigmoid; butterfly; park
      float s0 = P0 + blo(u2.x), s1 = P1 + bhi(u2.x);
      float s2 = P2 + blo(u2.y), s3 = P3 + bhi(u2.y);
      float acc;
      acc = qv.x * __builtin_amdgcn_rcpf(fexp2(s0) + 1.0f);
      acc = fmaf(qv.y, __builtin_amdgcn_rcpf(fexp2(s1) + 1.0f), acc);
      acc = fmaf(qv.z, __builtin_amdgcn_rcpf(fexp2(s2) + 1.0f), acc);
      acc = fmaf(qv.w, __builtin_amdgcn_rcpf(fexp2(s3) + 1.0f), acc);
      #pragma unroll
      for (int off = 1; off < 64; off <<= 1) acc += __shfl_xor(acc, off, 64);
      myscore = (lane == m - 1) ? acc : myscore;
    }
    // advance window: P' = Q + seg1(tok[m]); Q' = seg0(tok[m])
    P0 = Q0 + blo(u1.x); P1 = Q1 + bhi(u1.x);
    P2 = Q2 + blo(u1.y); P3 = Q3 + bhi(u1.y);
    Q0 = blo(u0.x); Q1 = bhi(u0.x);
    Q2 = blo(u0.y); Q3 = bhi(u0.y);
  }
  { // epilogue: s[29] complete (seg2(tok[30]) = 0)
    float acc;
    acc = qv.x * __builtin_amdgcn_rcpf(fexp2(P0) + 1.0f);
    acc = fmaf(qv.y, __builtin_amdgcn_rcpf(fexp2(P1) + 1.0f), acc);
    acc = fmaf(qv.z, __builtin_amdgcn_rcpf(fexp2(P2) + 1.0f), acc);
    acc = fmaf(qv.w, __builtin_amdgcn_rcpf(fexp2(P3) + 1.0f), acc);
    #pragma unroll
    for (int off = 1; off < 64; off <<= 1) acc += __shfl_xor(acc, off, 64);
    myscore = (lane == NW - 1) ? acc : myscore;
  }
  // |score| <= sum|q| ~ 16 -> exp safe in fp32; softmax needs no max-shift.
  float e = __expf(Qsum + myscore);
  if (lane < NW) expa[(size_t)b * EXPA_LD + lane] = e;
}

// ---------------------------------------------------------------------------
// Softmax-over-batch denominators, stage 1: 128 blocks x 256 titles each.
// part[n][blk] = sum over block's titles of expa[b][n].
// ---------------------------------------------------------------------------
__global__ __launch_bounds__(256) void softmax_part(const float* __restrict__ expa,
                                                    float* __restrict__ part) {
  __shared__ float P[256][33];
  int tid = threadIdx.x;
  const float* row = expa + (size_t)(blockIdx.x * 256 + tid) * EXPA_LD;
  #pragma unroll
  for (int j = 0; j < 7; ++j) {
    float4 vv = *(const float4*)(row + j * 4);
    P[tid][j * 4] = vv.x; P[tid][j * 4 + 1] = vv.y;
    P[tid][j * 4 + 2] = vv.z; P[tid][j * 4 + 3] = vv.w;
  }
  P[tid][28] = row[28]; P[tid][29] = row[29];
  __syncthreads();
  int wave = tid >> 6, lane = tid & 63;
  for (int n = wave * 8; n < wave * 8 + 8 && n < NW; ++n) {
    float s = P[lane * 4][n] + P[lane * 4 + 1][n] + P[lane * 4 + 2][n] + P[lane * 4 + 3][n];
    #pragma unroll
    for (int off = 32; off > 0; off >>= 1) s += __shfl_down(s, off, 64);
    if (lane == 0) part[n * 128 + blockIdx.x] = s;
  }
}

// Stage 2: rinv[n] = 1 / sum_blk part[n][blk]
__global__ void softmax_fin(const float* __restrict__ part, float* __restrict__ rinv) {
  int n = blockIdx.x;          // 30
  int lane = threadIdx.x;      // 64
  float s = part[n * 128 + lane] + part[n * 128 + 64 + lane];
  #pragma unroll
  for (int off = 32; off > 0; off >>= 1) s += __shfl_down(s, off, 64);
  if (lane == 0) rinv[n] = 1.0f / s;
}

// ---------------------------------------------------------------------------
// U[b, k*300+i] = sum_m alpha[b, m-k+1] * emb[tok[b,m], i]  -> bf16, stride 928
// Salpha[b] = sum_n alpha[b,n].  alpha = expa * rinv.
// ---------------------------------------------------------------------------
__global__ __launch_bounds__(192) void build_U(
    const int* __restrict__ tok, const unsigned short* __restrict__ embb,
    const float* __restrict__ expa, const float* __restrict__ rinv,
    unsigned short* __restrict__ U, float* __restrict__ Salpha) {
  int b = blockIdx.x;
  int tid = threadIdx.x;
  __shared__ float alpha[NW];
  __shared__ int ltok[NW];
  if (tid < NW) {
    ltok[tid] = tok[b * NW + tid];
    alpha[tid] = expa[(size_t)b * EXPA_LD + tid] * rinv[tid];
  }
  __syncthreads();
  if (tid == 0) {
    float s = 0.f;
    #pragma unroll
    for (int n = 0; n < NW; ++n) s += alpha[n];
    Salpha[b] = s;
  }
  unsigned short* Ub = U + (size_t)b * U_LD;
  if (tid < 150) {
    float a0 = 0.f, a1 = 0.f, a2 = 0.f;   // col x = 2*tid
    float b0 = 0.f, b1 = 0.f, b2 = 0.f;   // col y = 2*tid+1
    #pragma unroll 2
    for (int m = 0; m < NW; ++m) {
      int t = ltok[m];
      float w0 = (m + 1 < NW) ? alpha[m + 1] : 0.f;
      float w1 = alpha[m];
      float w2 = (m >= 1) ? alpha[m - 1] : 0.f;
      unsigned int u = *(const unsigned int*)(embb + (size_t)t * EMB_LD + 2 * tid);
      float x = blo(u), y = bhi(u);
      a0 = fmaf(w0, x, a0); b0 = fmaf(w0, y, b0);
      a1 = fmaf(w1, x, a1); b1 = fmaf(w1, y, b1);
      a2 = fmaf(w2, x, a2); b2 = fmaf(w2, y, b2);
    }
    *(unsigned int*)(Ub + 2 * tid)       = pack2bf(a0, b0);
    *(unsigned int*)(Ub + 300 + 2 * tid) = pack2bf(a1, b1);
    *(unsigned int*)(Ub + 600 + 2 * tid) = pack2bf(a2, b2);
  } else if (tid < 164) {
    *(unsigned int*)(Ub + 900 + 2 * (tid - 150)) = 0u;   // zero pad 900..927
  }
}

// ---------------------------------------------------------------------------
extern "C" void kernel_launch(void* const* d_in, const int* in_sizes, int n_in,
                              void* d_out, int out_size, void* d_ws, size_t ws_size,
                              hipStream_t stream) {
  const int*   tok    = (const int*)d_in[0];
  const float* emb    = (const float*)d_in[1];
  const float* conv_w = (const float*)d_in[2];
  const float* conv_b = (const float*)d_in[3];
  const float* v      = (const float*)d_in[4];
  const float* vb     = (const float*)d_in[5];
  const float* q      = (const float*)d_in[6];
  float* out = (float*)d_out;

  // Workspace layout (byte offsets). Total ~87.8 MB.
  char* wb = (char*)d_ws;
  float* bias2           = (float*)(wb + 0);          // 200 f32
  float* rinv            = (float*)(wb + 4096);       // 30 f32
  float* part            = (float*)(wb + 8192);       // 30*128 f32 -> 23552
  float* q2s             = (float*)(wb + 23552);      // 200 f32
  float* qsum            = (float*)(wb + 24448);      // 1 f32
  float* Salpha          = (float*)(wb + 24576);      // 32768 f32 -> 155648
  float* expa            = (float*)(wb + 155648);     // 32768*32 f32 -> 4349952
  float* Mt              = (float*)(wb + 4349952);    // 180000 f32 -> 5069952
  unsigned short* embb   = (unsigned short*)(wb + 5070848);   // 20.48MB -> 25550848
  unsigned short* MtT    = (unsigned short*)(wb + 25550848);  // 409600 -> 25960448
  unsigned short* WcT    = (unsigned short*)(wb + 25960448);  // 950272 -> 26910720
  unsigned short* big    = (unsigned short*)(wb + 26910720);  // E3 (41MB) / U (60.8MB)
  unsigned short* E3 = big;
  unsigned short* U  = big;   // E3 dead after scores_kernel

  // 1. Prep
  hipLaunchKernelGGL(prep_Mt_bias, dim3(902), dim3(200), 0, stream,
                     conv_w, conv_b, v, vb, q, Mt, bias2, q2s, qsum);
  hipLaunchKernelGGL(conv_MtT, dim3(E3_LD), dim3(EMB_LD), 0, stream, Mt, MtT);
  hipLaunchKernelGGL(prep_WcT, dim3(WCT_ROWS), dim3(256), 0, stream, conv_w, WcT);
  hipLaunchKernelGGL(prep_emb_bf16, dim3((VOCAB * EMB_LD) / 256), dim3(256), 0, stream,
                     emb, embb);
  // 2. E3[32000,640]bf16 = embb @ MtT^T (holds 2s*log2e), bias2 folded into cols [200,400)
  hipLaunchKernelGGL((gemm_mfma<true>), dim3(E3_LD / 128, VOCAB / 128), dim3(256), 0, stream,
                     embb, EMB_LD, MtT, EMB_LD, (void*)E3, E3_LD, E3_LD, EMB_LD,
                     (const float*)nullptr, (const float*)nullptr, bias2);
  // 3. exp(scores) -> expa[b][n]  (rolling-window gather; ZROW never touched)
  hipLaunchKernelGGL(scores_kernel, dim3(BT / 4), dim3(256), 0, stream,
                     tok, E3, q2s, qsum, expa);
  // 4. Softmax denominators (2-stage, deterministic)
  hipLaunchKernelGGL(softmax_part, dim3(128), dim3(256), 0, stream, expa, part);
  hipLaunchKernelGGL(softmax_fin, dim3(NW), dim3(64), 0, stream, part, rinv);
  // 5. U[32768,928]bf16 + Salpha
  hipLaunchKernelGGL(build_U, dim3(BT), dim3(192), 0, stream,
                     tok, embb, expa, rinv, U, Salpha);
  // 6. out[32768,400]f32 = U @ WcT^T + Salpha ⊗ conv_b
  hipLaunchKernelGGL((gemm_mfma<false>), dim3(WCT_ROWS / 128, BT / 128), dim3(256), 0, stream,
                     U, U_LD, WcT, U_LD, (void*)out, CH, CH, U_LD,
                     Salpha, conv_b, (const float*)nullptr);
}

// Round 3
// 438.879 us; speedup vs baseline: 1.1538x; 1.1494x over previous
//
#include <hip/hip_runtime.h>
#include <cstdint>
#include <cstddef>

// Problem constants
#define BT     32768   // batch (titles)
#define NW     30      // words per title
#define VOCAB  32000
#define WD     300     // word dim
#define CH     400     // conv channels
#define AD     200     // attention dim

// Padded layouts
#define EMB_LD   320   // emb_bf16 [VOCAB][320]  (300 + pad)
#define E3_LDB   640   // E3 int8 [VOCAB][640] bytes (600 + pad)
#define U_LD     928   // U bf16 [BT][928]       (900 + pad)
#define WCT_ROWS 512   // WcT bf16 [512][928]    (400 + pad rows)
#define EXPA_LD  32    // expa [BT][32]          (30 + pad)

#define TWO_LOG2E 2.8853900817779268f   // 2*log2(e): E3 holds 2s*log2e -> exp2 direct
#define QRANGE 14.0f                    // int8 scale range for E3 (~4 sigma; clips saturate tanh)
#define QSC  (127.0f / QRANGE)
#define QDEC (QRANGE / 127.0f)

typedef __attribute__((ext_vector_type(8))) short bf16x8;
typedef __attribute__((ext_vector_type(4))) float f32x4;

__device__ __forceinline__ float blo(unsigned int u) {
  union { unsigned int i; float f; } x; x.i = u << 16; return x.f;
}
__device__ __forceinline__ float bhi(unsigned int u) {
  union { unsigned int i; float f; } x; x.i = u & 0xffff0000u; return x.f;
}
__device__ __forceinline__ unsigned short f2bf(float f) {
  union { float f; unsigned int i; } x; x.f = f;
  unsigned int r = x.i + 0x7FFFu + ((x.i >> 16) & 1u);   // RNE
  return (unsigned short)(r >> 16);
}
__device__ __forceinline__ unsigned int pack2bf(float a, float b) {
  return (unsigned int)f2bf(a) | ((unsigned int)f2bf(b) << 16);
}
__device__ __forceinline__ float fexp2(float x) {
#if __has_builtin(__builtin_amdgcn_exp2f)
  return __builtin_amdgcn_exp2f(x);
#else
  float r; asm volatile("v_exp_f32 %0, %1" : "=v"(r) : "v"(x)); return r;
#endif
}
// signed byte j of packed u (emits v_bfe_i32)
#define SB(u, j) ((int)(signed char)(((u) >> (8 * (j))) & 0xffu))

// ---------------------------------------------------------------------------
// Fused prep (write-major over MtT):
// block n<640: MtT[n][i] = bf16(2*log2e * sum_c conv_w[c,i,k]*v[c,d]),
//              n = k*200+d, zero for n>=600 or i>=300.
// block 640: bias2[d] = 2*log2e * (sum_c conv_b[c]*v[c,d] + vb[d])
// block 641: q2s[d] = -2*q[d]; qsum[0] = sum_d q[d]
// ---------------------------------------------------------------------------
__global__ void prep_MtT_bias(const float* __restrict__ conv_w,
                              const float* __restrict__ conv_b,
                              const float* __restrict__ v,
                              const float* __restrict__ vb,
                              const float* __restrict__ q,
                              unsigned short* __restrict__ MtT,
                              float* __restrict__ bias2,
                              float* __restrict__ q2s,
                              float* __restrict__ qsum) {
  int blk = blockIdx.x;      // 0..639 -> MtT row; 640 -> bias2; 641 -> q2s/qsum
  int i = threadIdx.x;       // 0..319
  if (blk < 640) {
    float val = 0.f;
    if (blk < 600 && i < WD) {
      int k = blk / AD, d = blk - k * AD;
      float acc = 0.f;
      #pragma unroll 4
      for (int c = 0; c < CH; ++c)
        acc += conv_w[(c * WD + i) * 3 + k] * v[c * AD + d];
      val = TWO_LOG2E * acc;
    }
    MtT[blk * EMB_LD + i] = f2bf(val);
  } else if (blk == 640) {
    if (i < AD) {
      float acc = vb[i];
      #pragma unroll 4
      for (int c = 0; c < CH; ++c)
        acc += conv_b[c] * v[c * AD + i];
      bias2[i] = TWO_LOG2E * acc;
    }
  } else {
    if (i < AD) q2s[i] = -2.0f * q[i];
    if (i == 0) {
      float s = 0.f;
      for (int j = 0; j < AD; ++j) s += q[j];
      qsum[0] = s;
    }
  }
}

// WcT[c][kk] = bf16(conv_w[c, i, k]), kk = k*300+i; zero-padded. [512][928]
__global__ void prep_WcT(const float* __restrict__ conv_w, unsigned short* __restrict__ WcT) {
  int c = blockIdx.x;    // 512
  for (int kk = threadIdx.x; kk < U_LD; kk += 256) {
    float val = 0.f;
    if (c < CH && kk < 900) {
      int k = kk / WD, i = kk - k * WD;
      val = conv_w[(c * WD + i) * 3 + k];
    }
    WcT[(size_t)c * U_LD + kk] = f2bf(val);
  }
}

// emb -> bf16, zero-padded cols. [VOCAB][320]
__global__ void prep_emb_bf16(const float* __restrict__ emb, unsigned short* __restrict__ embb) {
  int idx = blockIdx.x * 256 + threadIdx.x;
  if (idx >= VOCAB * EMB_LD) return;
  int r = idx / EMB_LD, c = idx - r * EMB_LD;
  embb[idx] = (c < WD) ? f2bf(emb[(size_t)r * WD + c]) : (unsigned short)0;
}

// ---------------------------------------------------------------------------
// bf16 MFMA GEMM: C[M,N] = A[M,K] @ Bt[N,K]^T. 128x128 tile, K-step 32.
// MODE 1: int8 store (quantize by QSC), e3bias added to cols [200,400).
// MODE 0: fp32 store with col<N guard + rank-1 bias_m[r]*bias_n[c].
// XCD-chunked bijective block swizzle (m204) for A-panel L2 locality.
// ---------------------------------------------------------------------------
template<int MODE>
__global__ __launch_bounds__(256) void gemm_mfma(
    const unsigned short* __restrict__ A, int lda,
    const unsigned short* __restrict__ Bt, int ldb,
    void* __restrict__ Cp, int ldc, int N, int K,
    const float* __restrict__ bias_m, const float* __restrict__ bias_n,
    const float* __restrict__ e3bias) {
  __shared__ unsigned short As[128][40];   // +8 pad
  __shared__ unsigned short Bs[128][40];
  int tid = threadIdx.x;
  int lane = tid & 63, wave = tid >> 6;

  // XCD-aware bijective swizzle: contiguous tile chunks per XCD.
  int gx = gridDim.x;
  int nwg = gx * (int)gridDim.y;
  int orig = blockIdx.y * gx + blockIdx.x;
  int xcd = orig & 7, qq = nwg >> 3, rr = nwg & 7;
  int wg = (xcd < rr ? xcd * (qq + 1) : rr * (qq + 1) + (xcd - rr) * qq) + (orig >> 3);
  int row0 = (wg / gx) * 128, col0 = (wg % gx) * 128;

  int wm = (wave & 1) * 64, wn = (wave >> 1) * 64;
  int lr = lane & 15, quad = lane >> 4;

  f32x4 acc[4][4];
  #pragma unroll
  for (int i = 0; i < 4; ++i)
    #pragma unroll
    for (int j = 0; j < 4; ++j) acc[i][j] = (f32x4){0.f, 0.f, 0.f, 0.f};

  int r0 = tid >> 2, ko0 = (tid & 3) * 8;
  int r1 = (tid + 256) >> 2, ko1 = ((tid + 256) & 3) * 8;

  for (int k0 = 0; k0 < K; k0 += 32) {
    float4 av0 = *(const float4*)(A + (size_t)(row0 + r0) * lda + k0 + ko0);
    float4 av1 = *(const float4*)(A + (size_t)(row0 + r1) * lda + k0 + ko1);
    float4 bv0 = *(const float4*)(Bt + (size_t)(col0 + r0) * ldb + k0 + ko0);
    float4 bv1 = *(const float4*)(Bt + (size_t)(col0 + r1) * ldb + k0 + ko1);
    __syncthreads();
    *(float4*)&As[r0][ko0] = av0;
    *(float4*)&As[r1][ko1] = av1;
    *(float4*)&Bs[r0][ko0] = bv0;
    *(float4*)&Bs[r1][ko1] = bv1;
    __syncthreads();

    bf16x8 af[4], bfr[4];
    #pragma unroll
    for (int mi = 0; mi < 4; ++mi)
      af[mi] = *(const bf16x8*)&As[wm + mi * 16 + lr][quad * 8];
    #pragma unroll
    for (int ni = 0; ni < 4; ++ni)
      bfr[ni] = *(const bf16x8*)&Bs[wn + ni * 16 + lr][quad * 8];
    #pragma unroll
    for (int mi = 0; mi < 4; ++mi)
      #pragma unroll
      for (int ni = 0; ni < 4; ++ni)
        acc[mi][ni] = __builtin_amdgcn_mfma_f32_16x16x32_bf16(
            af[mi], bfr[ni], acc[mi][ni], 0, 0, 0);
  }

  // Epilogue. C/D layout: col = lane&15, row = quad*4 + reg.
  if (MODE == 1) {
    signed char* C = (signed char*)Cp;
    #pragma unroll
    for (int mi = 0; mi < 4; ++mi)
      #pragma unroll
      for (int ni = 0; ni < 4; ++ni) {
        int c = col0 + wn + ni * 16 + lr;
        float cb = (e3bias && c >= 200 && c < 400) ? e3bias[c - 200] : 0.f;
        #pragma unroll
        for (int reg = 0; reg < 4; ++reg) {
          int r = row0 + wm + mi * 16 + quad * 4 + reg;
          float x = (acc[mi][ni][reg] + cb) * QSC;
          int qi = (int)rintf(x);
          qi = qi > 127 ? 127 : (qi < -127 ? -127 : qi);
          C[(size_t)r * ldc + c] = (signed char)qi;
        }
      }
  } else {
    float* C = (float*)Cp;
    #pragma unroll
    for (int mi = 0; mi < 4; ++mi)
      #pragma unroll
      for (int ni = 0; ni < 4; ++ni) {
        int c = col0 + wn + ni * 16 + lr;
        if (c < N) {
          float bn = bias_n[c];
          #pragma unroll
          for (int reg = 0; reg < 4; ++reg) {
            int r = row0 + wm + mi * 16 + quad * 4 + reg;
            C[(size_t)r * ldc + c] = acc[mi][ni][reg] + bias_m[r] * bn;
          }
        }
      }
  }
}

// ---------------------------------------------------------------------------
// Scores, TITLE-per-wave, ROLLING-WINDOW over tokens, INT8 E3 (half bytes,
// 20.5MB table -> better L2 hit). Window partials kept as ints; one
// cvt+mul per dim at completion. E3 holds quant(2s*log2e) -> exp2 direct.
// score = Qsum + sum_d q2[d]/(exp2(QDEC*s_int_d)+1), q2 = -2q.
// ---------------------------------------------------------------------------
__global__ __launch_bounds__(256) void scores_kernel(
    const int* __restrict__ tok, const signed char* __restrict__ E3,
    const float* __restrict__ q2s, const float* __restrict__ qsum,
    float* __restrict__ expa) {
  __shared__ float qs[AD];
  int tid = threadIdx.x;
  if (tid < AD) qs[tid] = q2s[tid];
  __syncthreads();
  int wave = tid >> 6, lane = tid & 63;
  int b = blockIdx.x * 4 + wave;
  int tk = tok[b * NW + ((lane < NW) ? lane : 0)];
  int d0 = (lane < 50) ? lane * 4 : 0;
  float4 qv = make_float4(0.f, 0.f, 0.f, 0.f);
  if (lane < 50) qv = *(const float4*)&qs[d0];   // lanes >=50 contribute 0
  float Qsum = qsum[0];
  float myscore = 0.f;

  // Prefetch row tok[0]: three 4B segment loads off one base.
  int t0r = __shfl(tk, 0, 64);
  const signed char* r0p = E3 + (size_t)(unsigned)t0r * E3_LDB + d0;
  unsigned int a0 = *(const unsigned int*)(r0p);          // seg0 -> s[1]
  unsigned int a1 = *(const unsigned int*)(r0p + 200);    // seg1 -> s[0]
  unsigned int a2 = *(const unsigned int*)(r0p + 400);    // seg2 -> s[-1] (dropped)

  // Window partials (4 dims each), integer domain.
  int P0 = 0, P1 = 0, P2 = 0, P3 = 0;  // s[m-1] partial
  int Q0 = 0, Q1 = 0, Q2 = 0, Q3 = 0;  // s[m]   partial (seg0(tok[-1])=0)

  #pragma unroll
  for (int m = 0; m < NW; ++m) {
    unsigned int u0 = a0, u1 = a1, u2 = a2;
    if (m + 1 < NW) {   // prefetch next token's row (independent of below)
      int tn = __shfl(tk, m + 1, 64);
      const signed char* rp = E3 + (size_t)(unsigned)tn * E3_LDB + d0;
      a0 = *(const unsigned int*)(rp);
      a1 = *(const unsigned int*)(rp + 200);
      a2 = *(const unsigned int*)(rp + 400);
    }
    if (m > 0) {
      // complete s[m-1] with seg2 of current row; sigmoid; butterfly; park
      float s0 = QDEC * (float)(P0 + SB(u2, 0));
      float s1 = QDEC * (float)(P1 + SB(u2, 1));
      float s2 = QDEC * (float)(P2 + SB(u2, 2));
      float s3 = QDEC * (float)(P3 + SB(u2, 3));
      float acc;
      acc = qv.x * __builtin_amdgcn_rcpf(fexp2(s0) + 1.0f);
      acc = fmaf(qv.y, __builtin_amdgcn_rcpf(fexp2(s1) + 1.0f), acc);
      acc = fmaf(qv.z, __builtin_amdgcn_rcpf(fexp2(s2) + 1.0f), acc);
      acc = fmaf(qv.w, __builtin_amdgcn_rcpf(fexp2(s3) + 1.0f), acc);
      #pragma unroll
      for (int off = 1; off < 64; off <<= 1) acc += __shfl_xor(acc, off, 64);
      myscore = (lane == m - 1) ? acc : myscore;
    }
    // advance window: P' = Q + seg1(tok[m]); Q' = seg0(tok[m])
    P0 = Q0 + SB(u1, 0); P1 = Q1 + SB(u1, 1);
    P2 = Q2 + SB(u1, 2); P3 = Q3 + SB(u1, 3);
    Q0 = SB(u0, 0); Q1 = SB(u0, 1);
    Q2 = SB(u0, 2); Q3 = SB(u0, 3);
  }
  { // epilogue: s[29] complete (seg2(tok[30]) = 0)
    float s0 = QDEC * (float)P0, s1 = QDEC * (float)P1;
    float s2 = QDEC * (float)P2, s3 = QDEC * (float)P3;
    float acc;
    acc = qv.x * __builtin_amdgcn_rcpf(fexp2(s0) + 1.0f);
    acc = fmaf(qv.y, __builtin_amdgcn_rcpf(fexp2(s1) + 1.0f), acc);
    acc = fmaf(qv.z, __builtin_amdgcn_rcpf(fexp2(s2) + 1.0f), acc);
    acc = fmaf(qv.w, __builtin_amdgcn_rcpf(fexp2(s3) + 1.0f), acc);
    #pragma unroll
    for (int off = 1; off < 64; off <<= 1) acc += __shfl_xor(acc, off, 64);
    myscore = (lane == NW - 1) ? acc : myscore;
  }
  // |score| <= sum|q| ~ 16 -> exp safe in fp32; softmax needs no max-shift.
  float e = __expf(Qsum + myscore);
  if (lane < NW) expa[(size_t)b * EXPA_LD + lane] = e;
}

// ---------------------------------------------------------------------------
// Softmax-over-batch denominators, stage 1: 128 blocks x 256 titles each.
// part[n][blk] = sum over block's titles of expa[b][n].
// ---------------------------------------------------------------------------
__global__ __launch_bounds__(256) void softmax_part(const float* __restrict__ expa,
                                                    float* __restrict__ part) {
  __shared__ float P[256][33];
  int tid = threadIdx.x;
  const float* row = expa + (size_t)(blockIdx.x * 256 + tid) * EXPA_LD;
  #pragma unroll
  for (int j = 0; j < 7; ++j) {
    float4 vv = *(const float4*)(row + j * 4);
    P[tid][j * 4] = vv.x; P[tid][j * 4 + 1] = vv.y;
    P[tid][j * 4 + 2] = vv.z; P[tid][j * 4 + 3] = vv.w;
  }
  P[tid][28] = row[28]; P[tid][29] = row[29];
  __syncthreads();
  int wave = tid >> 6, lane = tid & 63;
  for (int n = wave * 8; n < wave * 8 + 8 && n < NW; ++n) {
    float s = P[lane * 4][n] + P[lane * 4 + 1][n] + P[lane * 4 + 2][n] + P[lane * 4 + 3][n];
    #pragma unroll
    for (int off = 32; off > 0; off >>= 1) s += __shfl_down(s, off, 64);
    if (lane == 0) part[n * 128 + blockIdx.x] = s;
  }
}

// Stage 2: rinv[n] = 1 / sum_blk part[n][blk]
__global__ void softmax_fin(const float* __restrict__ part, float* __restrict__ rinv) {
  int n = blockIdx.x;          // 30
  int lane = threadIdx.x;      // 64
  float s = part[n * 128 + lane] + part[n * 128 + 64 + lane];
  #pragma unroll
  for (int off = 32; off > 0; off >>= 1) s += __shfl_down(s, off, 64);
  if (lane == 0) rinv[n] = 1.0f / s;
}

// ---------------------------------------------------------------------------
// U[b, k*300+i] = sum_m alpha[b, m-k+1] * emb[tok[b,m], i]  -> bf16, stride 928
// Salpha[b] = sum_n alpha[b,n].  alpha = expa * rinv.
// ---------------------------------------------------------------------------
__global__ __launch_bounds__(192) void build_U(
    const int* __restrict__ tok, const unsigned short* __restrict__ embb,
    const float* __restrict__ expa, const float* __restrict__ rinv,
    unsigned short* __restrict__ U, float* __restrict__ Salpha) {
  int b = blockIdx.x;
  int tid = threadIdx.x;
  __shared__ float alpha[NW];
  __shared__ int ltok[NW];
  if (tid < NW) {
    ltok[tid] = tok[b * NW + tid];
    alpha[tid] = expa[(size_t)b * EXPA_LD + tid] * rinv[tid];
  }
  __syncthreads();
  if (tid == 0) {
    float s = 0.f;
    #pragma unroll
    for (int n = 0; n < NW; ++n) s += alpha[n];
    Salpha[b] = s;
  }
  unsigned short* Ub = U + (size_t)b * U_LD;
  if (tid < 150) {
    float a0 = 0.f, a1 = 0.f, a2 = 0.f;   // col x = 2*tid
    float b0 = 0.f, b1 = 0.f, b2 = 0.f;   // col y = 2*tid+1
    #pragma unroll 2
    for (int m = 0; m < NW; ++m) {
      int t = ltok[m];
      float w0 = (m + 1 < NW) ? alpha[m + 1] : 0.f;
      float w1 = alpha[m];
      float w2 = (m >= 1) ? alpha[m - 1] : 0.f;
      unsigned int u = *(const unsigned int*)(embb + (size_t)t * EMB_LD + 2 * tid);
      float x = blo(u), y = bhi(u);
      a0 = fmaf(w0, x, a0); b0 = fmaf(w0, y, b0);
      a1 = fmaf(w1, x, a1); b1 = fmaf(w1, y, b1);
      a2 = fmaf(w2, x, a2); b2 = fmaf(w2, y, b2);
    }
    *(unsigned int*)(Ub + 2 * tid)       = pack2bf(a0, b0);
    *(unsigned int*)(Ub + 300 + 2 * tid) = pack2bf(a1, b1);
    *(unsigned int*)(Ub + 600 + 2 * tid) = pack2bf(a2, b2);
  } else if (tid < 164) {
    *(unsigned int*)(Ub + 900 + 2 * (tid - 150)) = 0u;   // zero pad 900..927
  }
}

// ---------------------------------------------------------------------------
extern "C" void kernel_launch(void* const* d_in, const int* in_sizes, int n_in,
                              void* d_out, int out_size, void* d_ws, size_t ws_size,
                              hipStream_t stream) {
  const int*   tok    = (const int*)d_in[0];
  const float* emb    = (const float*)d_in[1];
  const float* conv_w = (const float*)d_in[2];
  const float* conv_b = (const float*)d_in[3];
  const float* v      = (const float*)d_in[4];
  const float* vb     = (const float*)d_in[5];
  const float* q      = (const float*)d_in[6];
  float* out = (float*)d_out;

  // Workspace layout (byte offsets). Total ~87.8 MB (unchanged map; Mt slot unused).
  char* wb = (char*)d_ws;
  float* bias2           = (float*)(wb + 0);          // 200 f32
  float* rinv            = (float*)(wb + 4096);       // 30 f32
  float* part            = (float*)(wb + 8192);       // 30*128 f32 -> 23552
  float* q2s             = (float*)(wb + 23552);      // 200 f32
  float* qsum            = (float*)(wb + 24448);      // 1 f32
  float* Salpha          = (float*)(wb + 24576);      // 32768 f32 -> 155648
  float* expa            = (float*)(wb + 155648);     // 32768*32 f32 -> 4349952
  unsigned short* embb   = (unsigned short*)(wb + 5070848);   // 20.48MB -> 25550848
  unsigned short* MtT    = (unsigned short*)(wb + 25550848);  // 409600 -> 25960448
  unsigned short* WcT    = (unsigned short*)(wb + 25960448);  // 950272 -> 26910720
  unsigned short* big    = (unsigned short*)(wb + 26910720);  // E3 i8 (20.5MB) / U (60.8MB)
  signed char* E3 = (signed char*)big;
  unsigned short* U = big;   // E3 dead after scores_kernel

  // 1. Prep
  hipLaunchKernelGGL(prep_MtT_bias, dim3(642), dim3(320), 0, stream,
                     conv_w, conv_b, v, vb, q, MtT, bias2, q2s, qsum);
  hipLaunchKernelGGL(prep_WcT, dim3(WCT_ROWS), dim3(256), 0, stream, conv_w, WcT);
  hipLaunchKernelGGL(prep_emb_bf16, dim3((VOCAB * EMB_LD) / 256), dim3(256), 0, stream,
                     emb, embb);
  // 2. E3[32000,640]i8 = quant(embb @ MtT^T), bias2 folded into cols [200,400)
  hipLaunchKernelGGL((gemm_mfma<1>), dim3(E3_LDB / 128, VOCAB / 128), dim3(256), 0, stream,
                     embb, EMB_LD, MtT, EMB_LD, (void*)E3, E3_LDB, E3_LDB, EMB_LD,
                     (const float*)nullptr, (const float*)nullptr, bias2);
  // 3. exp(scores) -> expa[b][n]  (rolling-window int8 gather)
  hipLaunchKernelGGL(scores_kernel, dim3(BT / 4), dim3(256), 0, stream,
                     tok, E3, q2s, qsum, expa);
  // 4. Softmax denominators (2-stage, deterministic)
  hipLaunchKernelGGL(softmax_part, dim3(128), dim3(256), 0, stream, expa, part);
  hipLaunchKernelGGL(softmax_fin, dim3(NW), dim3(64), 0, stream, part, rinv);
  // 5. U[32768,928]bf16 + Salpha
  hipLaunchKernelGGL(build_U, dim3(BT), dim3(192), 0, stream,
                     tok, embb, expa, rinv, U, Salpha);
  // 6. out[32768,400]f32 = U @ WcT^T + Salpha ⊗ conv_b
  hipLaunchKernelGGL((gemm_mfma<0>), dim3(WCT_ROWS / 128, BT / 128), dim3(256), 0, stream,
                     U, U_LD, WcT, U_LD, (void*)out, CH, CH, U_LD,
                     Salpha, conv_b, (const float*)nullptr);
}

// Round 4
// 420.181 us; speedup vs baseline: 1.2052x; 1.0445x over previous
//
#include <hip/hip_runtime.h>
#include <cstdint>
#include <cstddef>

// Problem constants
#define BT     32768   // batch (titles)
#define NW     30      // words per title
#define VOCAB  32000
#define WD     300     // word dim
#define CH     400     // conv channels
#define AD     200     // attention dim

// Padded layouts
#define EMB_LD   320   // emb_bf16 [VOCAB][320]  (300 + pad)
#define E3_LDB   640   // E3 uint8 [VOCAB][640] bytes (600 + pad), biased +128
#define U_LD     928   // U bf16 [BT][928]       (900 + pad)
#define WCT_ROWS 512   // WcT bf16 [512][928]    (400 + pad rows)
#define EXPA_LD  32    // expa [BT][32]          (30 + pad)

#define TWO_LOG2E 2.8853900817779268f   // 2*log2(e): E3 holds 2s*log2e -> exp2 direct
#define QRANGE 14.0f                    // int8 scale range for E3 (~4 sigma; clips saturate tanh)
#define QSC  (127.0f / QRANGE)
#define QDEC (QRANGE / 127.0f)
#define QB3  (-384.0f * QDEC)           // 3-segment byte bias (each byte +128)

typedef __attribute__((ext_vector_type(8))) short bf16x8;
typedef __attribute__((ext_vector_type(4))) float f32x4;

__device__ __forceinline__ float blo(unsigned int u) {
  union { unsigned int i; float f; } x; x.i = u << 16; return x.f;
}
__device__ __forceinline__ float bhi(unsigned int u) {
  union { unsigned int i; float f; } x; x.i = u & 0xffff0000u; return x.f;
}
__device__ __forceinline__ unsigned short f2bf(float f) {
  union { float f; unsigned int i; } x; x.f = f;
  unsigned int r = x.i + 0x7FFFu + ((x.i >> 16) & 1u);   // RNE
  return (unsigned short)(r >> 16);
}
__device__ __forceinline__ unsigned int pack2bf(float a, float b) {
  return (unsigned int)f2bf(a) | ((unsigned int)f2bf(b) << 16);
}
__device__ __forceinline__ float fexp2(float x) {
#if __has_builtin(__builtin_amdgcn_exp2f)
  return __builtin_amdgcn_exp2f(x);
#else
  float r; asm volatile("v_exp_f32 %0, %1" : "=v"(r) : "v"(x)); return r;
#endif
}
// unsigned byte j of packed u, as float (matches v_cvt_f32_ubyteN pattern)
#define UBF(u, j) ((float)(((u) >> (8 * (j))) & 0xffu))

// ---------------------------------------------------------------------------
// Fused prep (write-major over MtT):
// block n<640: MtT[n][i] = bf16(2*log2e * sum_c conv_w[c,i,k]*v[c,d]),
//              n = k*200+d, zero for n>=600 or i>=300.
// block 640: bias2[d] = 2*log2e * (sum_c conv_b[c]*v[c,d] + vb[d])
// block 641: q2s[d] = -2*q[d]; qsum[0] = sum_d q[d]
// ---------------------------------------------------------------------------
__global__ void prep_MtT_bias(const float* __restrict__ conv_w,
                              const float* __restrict__ conv_b,
                              const float* __restrict__ v,
                              const float* __restrict__ vb,
                              const float* __restrict__ q,
                              unsigned short* __restrict__ MtT,
                              float* __restrict__ bias2,
                              float* __restrict__ q2s,
                              float* __restrict__ qsum) {
  int blk = blockIdx.x;      // 0..639 -> MtT row; 640 -> bias2; 641 -> q2s/qsum
  int i = threadIdx.x;       // 0..319
  if (blk < 640) {
    float val = 0.f;
    if (blk < 600 && i < WD) {
      int k = blk / AD, d = blk - k * AD;
      float acc = 0.f;
      #pragma unroll 4
      for (int c = 0; c < CH; ++c)
        acc += conv_w[(c * WD + i) * 3 + k] * v[c * AD + d];
      val = TWO_LOG2E * acc;
    }
    MtT[blk * EMB_LD + i] = f2bf(val);
  } else if (blk == 640) {
    if (i < AD) {
      float acc = vb[i];
      #pragma unroll 4
      for (int c = 0; c < CH; ++c)
        acc += conv_b[c] * v[c * AD + i];
      bias2[i] = TWO_LOG2E * acc;
    }
  } else {
    if (i < AD) q2s[i] = -2.0f * q[i];
    if (i == 0) {
      float s = 0.f;
      for (int j = 0; j < AD; ++j) s += q[j];
      qsum[0] = s;
    }
  }
}

// WcT[c][kk] = bf16(conv_w[c, i, k]), kk = k*300+i; zero-padded. [512][928]
__global__ void prep_WcT(const float* __restrict__ conv_w, unsigned short* __restrict__ WcT) {
  int c = blockIdx.x;    // 512
  for (int kk = threadIdx.x; kk < U_LD; kk += 256) {
    float val = 0.f;
    if (c < CH && kk < 900) {
      int k = kk / WD, i = kk - k * WD;
      val = conv_w[(c * WD + i) * 3 + k];
    }
    WcT[(size_t)c * U_LD + kk] = f2bf(val);
  }
}

// emb -> bf16, zero-padded cols. [VOCAB][320]
__global__ void prep_emb_bf16(const float* __restrict__ emb, unsigned short* __restrict__ embb) {
  int idx = blockIdx.x * 256 + threadIdx.x;
  if (idx >= VOCAB * EMB_LD) return;
  int r = idx / EMB_LD, c = idx - r * EMB_LD;
  embb[idx] = (c < WD) ? f2bf(emb[(size_t)r * WD + c]) : (unsigned short)0;
}

// ---------------------------------------------------------------------------
// bf16 MFMA GEMM: C[M,N] = A[M,K] @ Bt[N,K]^T. 128x128 tile, K-step 32.
// MODE 1: biased-uint8 store (quantize by QSC, +128), e3bias on cols [200,400).
// MODE 0: fp32 store with col<N guard + rank-1 bias_m[r]*bias_n[c].
// XCD-chunked bijective block swizzle (m204) for A-panel L2 locality.
// ---------------------------------------------------------------------------
template<int MODE>
__global__ __launch_bounds__(256) void gemm_mfma(
    const unsigned short* __restrict__ A, int lda,
    const unsigned short* __restrict__ Bt, int ldb,
    void* __restrict__ Cp, int ldc, int N, int K,
    const float* __restrict__ bias_m, const float* __restrict__ bias_n,
    const float* __restrict__ e3bias) {
  __shared__ unsigned short As[128][40];   // +8 pad
  __shared__ unsigned short Bs[128][40];
  int tid = threadIdx.x;
  int lane = tid & 63, wave = tid >> 6;

  // XCD-aware bijective swizzle: contiguous tile chunks per XCD.
  int gx = gridDim.x;
  int nwg = gx * (int)gridDim.y;
  int orig = blockIdx.y * gx + blockIdx.x;
  int xcd = orig & 7, qq = nwg >> 3, rr = nwg & 7;
  int wg = (xcd < rr ? xcd * (qq + 1) : rr * (qq + 1) + (xcd - rr) * qq) + (orig >> 3);
  int row0 = (wg / gx) * 128, col0 = (wg % gx) * 128;

  int wm = (wave & 1) * 64, wn = (wave >> 1) * 64;
  int lr = lane & 15, quad = lane >> 4;

  f32x4 acc[4][4];
  #pragma unroll
  for (int i = 0; i < 4; ++i)
    #pragma unroll
    for (int j = 0; j < 4; ++j) acc[i][j] = (f32x4){0.f, 0.f, 0.f, 0.f};

  int r0 = tid >> 2, ko0 = (tid & 3) * 8;
  int r1 = (tid + 256) >> 2, ko1 = ((tid + 256) & 3) * 8;

  for (int k0 = 0; k0 < K; k0 += 32) {
    float4 av0 = *(const float4*)(A + (size_t)(row0 + r0) * lda + k0 + ko0);
    float4 av1 = *(const float4*)(A + (size_t)(row0 + r1) * lda + k0 + ko1);
    float4 bv0 = *(const float4*)(Bt + (size_t)(col0 + r0) * ldb + k0 + ko0);
    float4 bv1 = *(const float4*)(Bt + (size_t)(col0 + r1) * ldb + k0 + ko1);
    __syncthreads();
    *(float4*)&As[r0][ko0] = av0;
    *(float4*)&As[r1][ko1] = av1;
    *(float4*)&Bs[r0][ko0] = bv0;
    *(float4*)&Bs[r1][ko1] = bv1;
    __syncthreads();

    bf16x8 af[4], bfr[4];
    #pragma unroll
    for (int mi = 0; mi < 4; ++mi)
      af[mi] = *(const bf16x8*)&As[wm + mi * 16 + lr][quad * 8];
    #pragma unroll
    for (int ni = 0; ni < 4; ++ni)
      bfr[ni] = *(const bf16x8*)&Bs[wn + ni * 16 + lr][quad * 8];
    #pragma unroll
    for (int mi = 0; mi < 4; ++mi)
      #pragma unroll
      for (int ni = 0; ni < 4; ++ni)
        acc[mi][ni] = __builtin_amdgcn_mfma_f32_16x16x32_bf16(
            af[mi], bfr[ni], acc[mi][ni], 0, 0, 0);
  }

  // Epilogue. C/D layout: col = lane&15, row = quad*4 + reg.
  if (MODE == 1) {
    unsigned char* C = (unsigned char*)Cp;
    #pragma unroll
    for (int mi = 0; mi < 4; ++mi)
      #pragma unroll
      for (int ni = 0; ni < 4; ++ni) {
        int c = col0 + wn + ni * 16 + lr;
        float cb = (e3bias && c >= 200 && c < 400) ? e3bias[c - 200] : 0.f;
        #pragma unroll
        for (int reg = 0; reg < 4; ++reg) {
          int r = row0 + wm + mi * 16 + quad * 4 + reg;
          float x = (acc[mi][ni][reg] + cb) * QSC;
          int qi = (int)rintf(x);
          qi = qi > 127 ? 127 : (qi < -127 ? -127 : qi);
          C[(size_t)r * ldc + c] = (unsigned char)(qi + 128);
        }
      }
  } else {
    float* C = (float*)Cp;
    #pragma unroll
    for (int mi = 0; mi < 4; ++mi)
      #pragma unroll
      for (int ni = 0; ni < 4; ++ni) {
        int c = col0 + wn + ni * 16 + lr;
        if (c < N) {
          float bn = bias_n[c];
          #pragma unroll
          for (int reg = 0; reg < 4; ++reg) {
            int r = row0 + wm + mi * 16 + quad * 4 + reg;
            C[(size_t)r * ldc + c] = acc[mi][ni][reg] + bias_m[r] * bn;
          }
        }
      }
  }
}

// ---------------------------------------------------------------------------
// Scores, TITLE-per-wave, ROLLING-WINDOW over tokens, biased-uint8 E3.
// VALU diet vs R3:
//  - bytes -> float via v_cvt_f32_ubyte pattern; fp32 window; bias folds
//    into the QDEC scale-fma (virtual edge segments = 128).
//  - pairwise rational: q0*sig0+q1*sig1 = [q0*e1+q1*e0+q0+q1]/[e0e1+e0+e1+1]
//    -> 2 rcp/iter instead of 4 (e<=2^42, products <2^84: no overflow).
//  - NO per-word butterfly: shfl_xor(1) pair pre-reduce, park 32 partials
//    per word in wave-private LDS, single transpose-reduce at the end.
// ---------------------------------------------------------------------------
__global__ __launch_bounds__(256) void scores_kernel(
    const int* __restrict__ tok, const unsigned char* __restrict__ E3,
    const float* __restrict__ q2s, const float* __restrict__ qsum,
    float* __restrict__ expa) {
  __shared__ float qs[AD];
  __shared__ __align__(16) float red[4][NW][36];   // stride 36 floats = 144B (16B aligned)
  int tid = threadIdx.x;
  if (tid < AD) qs[tid] = q2s[tid];
  __syncthreads();
  int wave = tid >> 6, lane = tid & 63;
  int b = blockIdx.x * 4 + wave;
  int tk = tok[b * NW + ((lane < NW) ? lane : 0)];
  int d0 = (lane < 50) ? lane * 4 : 0;
  float4 qv = make_float4(0.f, 0.f, 0.f, 0.f);
  if (lane < 50) qv = *(const float4*)&qs[d0];   // lanes >=50 contribute 0
  float s01 = qv.x + qv.y, s23 = qv.z + qv.w;
  float Qsum = qsum[0];
  float* myred = &red[wave][0][lane >> 1];       // word stride = 36 floats

  // Prefetch row tok[0]: three 4B segment loads off one base.
  int t0r = __shfl(tk, 0, 64);
  const unsigned char* r0p = E3 + (size_t)(unsigned)t0r * E3_LDB + d0;
  unsigned int a0 = *(const unsigned int*)(r0p);          // seg0 -> s[1]
  unsigned int a1 = *(const unsigned int*)(r0p + 200);    // seg1 -> s[0]
  unsigned int a2 = *(const unsigned int*)(r0p + 400);    // seg2 -> s[-1] (dropped)

  // fp32 window of biased bytes; virtual seg0(tok[-1]) = bias 128.
  float P0 = 0.f, P1 = 0.f, P2 = 0.f, P3 = 0.f;
  float Q0 = 128.f, Q1 = 128.f, Q2 = 128.f, Q3 = 128.f;

  #pragma unroll
  for (int m = 0; m < NW; ++m) {
    unsigned int u0 = a0, u1 = a1, u2 = a2;
    if (m + 1 < NW) {   // prefetch next token's row (independent of below)
      int tn = __shfl(tk, m + 1, 64);
      const unsigned char* rp = E3 + (size_t)(unsigned)tn * E3_LDB + d0;
      a0 = *(const unsigned int*)(rp);
      a1 = *(const unsigned int*)(rp + 200);
      a2 = *(const unsigned int*)(rp + 400);
    }
    if (m > 0) {
      // complete s[m-1] with seg2 of current row; sigmoid; pair-park.
      float e0 = fexp2(fmaf(P0 + UBF(u2, 0), QDEC, QB3));
      float e1 = fexp2(fmaf(P1 + UBF(u2, 1), QDEC, QB3));
      float e2 = fexp2(fmaf(P2 + UBF(u2, 2), QDEC, QB3));
      float e3 = fexp2(fmaf(P3 + UBF(u2, 3), QDEC, QB3));
      float n01 = fmaf(qv.x, e1, s01); n01 = fmaf(qv.y, e0, n01);
      float n23 = fmaf(qv.z, e3, s23); n23 = fmaf(qv.w, e2, n23);
      float d01 = fmaf(e0, e1, (e0 + e1) + 1.0f);
      float d23 = fmaf(e2, e3, (e2 + e3) + 1.0f);
      float acc = n01 * __builtin_amdgcn_rcpf(d01);
      acc = fmaf(n23, __builtin_amdgcn_rcpf(d23), acc);
      acc += __shfl_xor(acc, 1, 64);          // lanes 2k,2k+1 now equal
      myred[(m - 1) * 36] = acc;              // benign same-value dual write
    }
    // advance window: P' = Q + seg1(tok[m]); Q' = seg0(tok[m])
    P0 = Q0 + UBF(u1, 0); P1 = Q1 + UBF(u1, 1);
    P2 = Q2 + UBF(u1, 2); P3 = Q3 + UBF(u1, 3);
    Q0 = UBF(u0, 0); Q1 = UBF(u0, 1);
    Q2 = UBF(u0, 2); Q3 = UBF(u0, 3);
  }
  { // epilogue: s[29] complete; missing seg2 -> bias 128
    float e0 = fexp2(fmaf(P0 + 128.f, QDEC, QB3));
    float e1 = fexp2(fmaf(P1 + 128.f, QDEC, QB3));
    float e2 = fexp2(fmaf(P2 + 128.f, QDEC, QB3));
    float e3 = fexp2(fmaf(P3 + 128.f, QDEC, QB3));
    float n01 = fmaf(qv.x, e1, s01); n01 = fmaf(qv.y, e0, n01);
    float n23 = fmaf(qv.z, e3, s23); n23 = fmaf(qv.w, e2, n23);
    float d01 = fmaf(e0, e1, (e0 + e1) + 1.0f);
    float d23 = fmaf(e2, e3, (e2 + e3) + 1.0f);
    float acc = n01 * __builtin_amdgcn_rcpf(d01);
    acc = fmaf(n23, __builtin_amdgcn_rcpf(d23), acc);
    acc += __shfl_xor(acc, 1, 64);
    myred[(NW - 1) * 36] = acc;
  }
  __syncthreads();
  // Transpose-reduce: word n's 32 partials; lane n sums j=0..15, lane n+32
  // sums j=16..31; xor-32 combines. Lanes with n>=30 are dummies.
  int n = lane & 31; if (n >= NW) n = 0;
  int half = lane >> 5;
  const float4* rp4 = (const float4*)&red[wave][n][half * 16];
  float4 s4 = rp4[0];
  #pragma unroll
  for (int j = 1; j < 4; ++j) {
    float4 vv = rp4[j];
    s4.x += vv.x; s4.y += vv.y; s4.z += vv.z; s4.w += vv.w;
  }
  float tot = (s4.x + s4.y) + (s4.z + s4.w);
  tot += __shfl_xor(tot, 32, 64);
  // |score| <= sum|q| ~ 16 -> exp safe in fp32; softmax needs no max-shift.
  float e = __expf(Qsum + tot);
  if (lane < NW) expa[(size_t)b * EXPA_LD + lane] = e;
}

// ---------------------------------------------------------------------------
// Softmax-over-batch denominators, stage 1: 128 blocks x 256 titles each.
// part[n][blk] = sum over block's titles of expa[b][n].
// ---------------------------------------------------------------------------
__global__ __launch_bounds__(256) void softmax_part(const float* __restrict__ expa,
                                                    float* __restrict__ part) {
  __shared__ float P[256][33];
  int tid = threadIdx.x;
  const float* row = expa + (size_t)(blockIdx.x * 256 + tid) * EXPA_LD;
  #pragma unroll
  for (int j = 0; j < 7; ++j) {
    float4 vv = *(const float4*)(row + j * 4);
    P[tid][j * 4] = vv.x; P[tid][j * 4 + 1] = vv.y;
    P[tid][j * 4 + 2] = vv.z; P[tid][j * 4 + 3] = vv.w;
  }
  P[tid][28] = row[28]; P[tid][29] = row[29];
  __syncthreads();
  int wave = tid >> 6, lane = tid & 63;
  for (int n = wave * 8; n < wave * 8 + 8 && n < NW; ++n) {
    float s = P[lane * 4][n] + P[lane * 4 + 1][n] + P[lane * 4 + 2][n] + P[lane * 4 + 3][n];
    #pragma unroll
    for (int off = 32; off > 0; off >>= 1) s += __shfl_down(s, off, 64);
    if (lane == 0) part[n * 128 + blockIdx.x] = s;
  }
}

// Stage 2: rinv[n] = 1 / sum_blk part[n][blk]
__global__ void softmax_fin(const float* __restrict__ part, float* __restrict__ rinv) {
  int n = blockIdx.x;          // 30
  int lane = threadIdx.x;      // 64
  float s = part[n * 128 + lane] + part[n * 128 + 64 + lane];
  #pragma unroll
  for (int off = 32; off > 0; off >>= 1) s += __shfl_down(s, off, 64);
  if (lane == 0) rinv[n] = 1.0f / s;
}

// ---------------------------------------------------------------------------
// U[b, k*300+i] = sum_m alpha[b, m-k+1] * emb[tok[b,m], i]  -> bf16, stride 928
// Salpha[b] = sum_n alpha[b,n].  alpha = expa * rinv.
// ---------------------------------------------------------------------------
__global__ __launch_bounds__(192) void build_U(
    const int* __restrict__ tok, const unsigned short* __restrict__ embb,
    const float* __restrict__ expa, const float* __restrict__ rinv,
    unsigned short* __restrict__ U, float* __restrict__ Salpha) {
  int b = blockIdx.x;
  int tid = threadIdx.x;
  __shared__ float alpha[NW];
  __shared__ int ltok[NW];
  if (tid < NW) {
    ltok[tid] = tok[b * NW + tid];
    alpha[tid] = expa[(size_t)b * EXPA_LD + tid] * rinv[tid];
  }
  __syncthreads();
  if (tid == 0) {
    float s = 0.f;
    #pragma unroll
    for (int n = 0; n < NW; ++n) s += alpha[n];
    Salpha[b] = s;
  }
  unsigned short* Ub = U + (size_t)b * U_LD;
  if (tid < 150) {
    float a0 = 0.f, a1 = 0.f, a2 = 0.f;   // col x = 2*tid
    float b0 = 0.f, b1 = 0.f, b2 = 0.f;   // col y = 2*tid+1
    #pragma unroll 2
    for (int m = 0; m < NW; ++m) {
      int t = ltok[m];
      float w0 = (m + 1 < NW) ? alpha[m + 1] : 0.f;
      float w1 = alpha[m];
      float w2 = (m >= 1) ? alpha[m - 1] : 0.f;
      unsigned int u = *(const unsigned int*)(embb + (size_t)t * EMB_LD + 2 * tid);
      float x = blo(u), y = bhi(u);
      a0 = fmaf(w0, x, a0); b0 = fmaf(w0, y, b0);
      a1 = fmaf(w1, x, a1); b1 = fmaf(w1, y, b1);
      a2 = fmaf(w2, x, a2); b2 = fmaf(w2, y, b2);
    }
    *(unsigned int*)(Ub + 2 * tid)       = pack2bf(a0, b0);
    *(unsigned int*)(Ub + 300 + 2 * tid) = pack2bf(a1, b1);
    *(unsigned int*)(Ub + 600 + 2 * tid) = pack2bf(a2, b2);
  } else if (tid < 164) {
    *(unsigned int*)(Ub + 900 + 2 * (tid - 150)) = 0u;   // zero pad 900..927
  }
}

// ---------------------------------------------------------------------------
extern "C" void kernel_launch(void* const* d_in, const int* in_sizes, int n_in,
                              void* d_out, int out_size, void* d_ws, size_t ws_size,
                              hipStream_t stream) {
  const int*   tok    = (const int*)d_in[0];
  const float* emb    = (const float*)d_in[1];
  const float* conv_w = (const float*)d_in[2];
  const float* conv_b = (const float*)d_in[3];
  const float* v      = (const float*)d_in[4];
  const float* vb     = (const float*)d_in[5];
  const float* q      = (const float*)d_in[6];
  float* out = (float*)d_out;

  // Workspace layout (byte offsets). Total ~87.8 MB.
  char* wb = (char*)d_ws;
  float* bias2           = (float*)(wb + 0);          // 200 f32
  float* rinv            = (float*)(wb + 4096);       // 30 f32
  float* part            = (float*)(wb + 8192);       // 30*128 f32 -> 23552
  float* q2s             = (float*)(wb + 23552);      // 200 f32
  float* qsum            = (float*)(wb + 24448);      // 1 f32
  float* Salpha          = (float*)(wb + 24576);      // 32768 f32 -> 155648
  float* expa            = (float*)(wb + 155648);     // 32768*32 f32 -> 4349952
  unsigned short* embb   = (unsigned short*)(wb + 5070848);   // 20.48MB -> 25550848
  unsigned short* MtT    = (unsigned short*)(wb + 25550848);  // 409600 -> 25960448
  unsigned short* WcT    = (unsigned short*)(wb + 25960448);  // 950272 -> 26910720
  unsigned short* big    = (unsigned short*)(wb + 26910720);  // E3 u8 (20.5MB) / U (60.8MB)
  unsigned char* E3 = (unsigned char*)big;
  unsigned short* U = big;   // E3 dead after scores_kernel

  // 1. Prep
  hipLaunchKernelGGL(prep_MtT_bias, dim3(642), dim3(320), 0, stream,
                     conv_w, conv_b, v, vb, q, MtT, bias2, q2s, qsum);
  hipLaunchKernelGGL(prep_WcT, dim3(WCT_ROWS), dim3(256), 0, stream, conv_w, WcT);
  hipLaunchKernelGGL(prep_emb_bf16, dim3((VOCAB * EMB_LD) / 256), dim3(256), 0, stream,
                     emb, embb);
  // 2. E3[32000,640]u8 = quant(embb @ MtT^T)+128, bias2 folded into cols [200,400)
  hipLaunchKernelGGL((gemm_mfma<1>), dim3(E3_LDB / 128, VOCAB / 128), dim3(256), 0, stream,
                     embb, EMB_LD, MtT, EMB_LD, (void*)E3, E3_LDB, E3_LDB, EMB_LD,
                     (const float*)nullptr, (const float*)nullptr, bias2);
  // 3. exp(scores) -> expa[b][n]  (rolling-window uint8 gather, LDS reduce)
  hipLaunchKernelGGL(scores_kernel, dim3(BT / 4), dim3(256), 0, stream,
                     tok, E3, q2s, qsum, expa);
  // 4. Softmax denominators (2-stage, deterministic)
  hipLaunchKernelGGL(softmax_part, dim3(128), dim3(256), 0, stream, expa, part);
  hipLaunchKernelGGL(softmax_fin, dim3(NW), dim3(64), 0, stream, part, rinv);
  // 5. U[32768,928]bf16 + Salpha
  hipLaunchKernelGGL(build_U, dim3(BT), dim3(192), 0, stream,
                     tok, embb, expa, rinv, U, Salpha);
  // 6. out[32768,400]f32 = U @ WcT^T + Salpha ⊗ conv_b
  hipLaunchKernelGGL((gemm_mfma<0>), dim3(WCT_ROWS / 128, BT / 128), dim3(256), 0, stream,
                     U, U_LD, WcT, U_LD, (void*)out, CH, CH, U_LD,
                     Salpha, conv_b, (const float*)nullptr);
}

// Round 5
// 401.472 us; speedup vs baseline: 1.2613x; 1.0466x over previous
//
#include <hip/hip_runtime.h>
#include <cstdint>
#include <cstddef>

// Problem constants
#define BT     32768   // batch (titles)
#define NW     30      // words per title
#define VOCAB  32000
#define WD     300     // word dim
#define CH     400     // conv channels
#define AD     200     // attention dim

// Padded layouts
#define EMB_LD   320   // emb_bf16 [VOCAB][320]  (300 + pad)
#define E3_LDB   640   // E3 uint8 [VOCAB][640] bytes (600 + pad), biased +128
#define U_LD     928   // U bf16 [BT][928]       (900 + pad)
#define WCT_ROWS 512   // WcT bf16 [512][928]    (400 + pad rows)
#define EXPA_LD  32    // expa [BT][32]          (30 + pad)

#define TWO_LOG2E 2.8853900817779268f   // 2*log2(e): E3 holds 2s*log2e -> exp2 direct
#define QRANGE 14.0f                    // int8 scale range for E3 (~4 sigma; clips saturate tanh)
#define QSC  (127.0f / QRANGE)
#define QDEC (QRANGE / 127.0f)
#define QB3  (-384.0f * QDEC)           // 3-segment byte bias (each byte +128)

typedef __attribute__((ext_vector_type(8))) short bf16x8;
typedef __attribute__((ext_vector_type(4))) float f32x4;

__device__ __forceinline__ float blo(unsigned int u) {
  union { unsigned int i; float f; } x; x.i = u << 16; return x.f;
}
__device__ __forceinline__ float bhi(unsigned int u) {
  union { unsigned int i; float f; } x; x.i = u & 0xffff0000u; return x.f;
}
__device__ __forceinline__ unsigned short f2bf(float f) {
  union { float f; unsigned int i; } x; x.f = f;
  unsigned int r = x.i + 0x7FFFu + ((x.i >> 16) & 1u);   // RNE
  return (unsigned short)(r >> 16);
}
__device__ __forceinline__ unsigned int pack2bf(float a, float b) {
  return (unsigned int)f2bf(a) | ((unsigned int)f2bf(b) << 16);
}
__device__ __forceinline__ float fexp2(float x) {
#if __has_builtin(__builtin_amdgcn_exp2f)
  return __builtin_amdgcn_exp2f(x);
#else
  float r; asm volatile("v_exp_f32 %0, %1" : "=v"(r) : "v"(x)); return r;
#endif
}
// unsigned byte j of packed u, as float (matches v_cvt_f32_ubyteN pattern)
#define UBF(u, j) ((float)(((u) >> (8 * (j))) & 0xffu))

// ---------------------------------------------------------------------------
// Fused prep (write-major over MtT):
// block n<640: MtT[n][i] = bf16(2*log2e * sum_c conv_w[c,i,k]*v[c,d]),
//              n = k*200+d, zero for n>=600 or i>=300.
// block 640: bias2[d] = 2*log2e * (sum_c conv_b[c]*v[c,d] + vb[d])
// block 641: q2s[d] = -2*q[d]; qsum[0] = sum_d q[d]
// ---------------------------------------------------------------------------
__global__ void prep_MtT_bias(const float* __restrict__ conv_w,
                              const float* __restrict__ conv_b,
                              const float* __restrict__ v,
                              const float* __restrict__ vb,
                              const float* __restrict__ q,
                              unsigned short* __restrict__ MtT,
                              float* __restrict__ bias2,
                              float* __restrict__ q2s,
                              float* __restrict__ qsum) {
  int blk = blockIdx.x;      // 0..639 -> MtT row; 640 -> bias2; 641 -> q2s/qsum
  int i = threadIdx.x;       // 0..319
  if (blk < 640) {
    float val = 0.f;
    if (blk < 600 && i < WD) {
      int k = blk / AD, d = blk - k * AD;
      float acc = 0.f;
      #pragma unroll 4
      for (int c = 0; c < CH; ++c)
        acc += conv_w[(c * WD + i) * 3 + k] * v[c * AD + d];
      val = TWO_LOG2E * acc;
    }
    MtT[blk * EMB_LD + i] = f2bf(val);
  } else if (blk == 640) {
    if (i < AD) {
      float acc = vb[i];
      #pragma unroll 4
      for (int c = 0; c < CH; ++c)
        acc += conv_b[c] * v[c * AD + i];
      bias2[i] = TWO_LOG2E * acc;
    }
  } else {
    if (i < AD) q2s[i] = -2.0f * q[i];
    if (i == 0) {
      float s = 0.f;
      for (int j = 0; j < AD; ++j) s += q[j];
      qsum[0] = s;
    }
  }
}

// WcT[c][kk] = bf16(conv_w[c, i, k]), kk = k*300+i; zero-padded. [512][928]
__global__ void prep_WcT(const float* __restrict__ conv_w, unsigned short* __restrict__ WcT) {
  int c = blockIdx.x;    // 512
  for (int kk = threadIdx.x; kk < U_LD; kk += 256) {
    float val = 0.f;
    if (c < CH && kk < 900) {
      int k = kk / WD, i = kk - k * WD;
      val = conv_w[(c * WD + i) * 3 + k];
    }
    WcT[(size_t)c * U_LD + kk] = f2bf(val);
  }
}

// emb -> bf16, zero-padded cols. [VOCAB][320]
__global__ void prep_emb_bf16(const float* __restrict__ emb, unsigned short* __restrict__ embb) {
  int idx = blockIdx.x * 256 + threadIdx.x;
  if (idx >= VOCAB * EMB_LD) return;
  int r = idx / EMB_LD, c = idx - r * EMB_LD;
  embb[idx] = (c < WD) ? f2bf(emb[(size_t)r * WD + c]) : (unsigned short)0;
}

// ---------------------------------------------------------------------------
// bf16 MFMA GEMM: C[M,N] = A[M,K] @ Bt[N,K]^T. 128x128 tile, K-step 32.
// MODE 1: biased-uint8 store (quantize by QSC, +128), e3bias on cols [200,400).
// MODE 0: fp32 store with col<N guard + rank-1 bias_m[r]*bias_n[c].
// XCD-chunked bijective block swizzle (m204) for A-panel L2 locality.
// ---------------------------------------------------------------------------
template<int MODE>
__global__ __launch_bounds__(256) void gemm_mfma(
    const unsigned short* __restrict__ A, int lda,
    const unsigned short* __restrict__ Bt, int ldb,
    void* __restrict__ Cp, int ldc, int N, int K,
    const float* __restrict__ bias_m, const float* __restrict__ bias_n,
    const float* __restrict__ e3bias) {
  __shared__ unsigned short As[128][40];   // +8 pad
  __shared__ unsigned short Bs[128][40];
  int tid = threadIdx.x;
  int lane = tid & 63, wave = tid >> 6;

  // XCD-aware bijective swizzle: contiguous tile chunks per XCD.
  int gx = gridDim.x;
  int nwg = gx * (int)gridDim.y;
  int orig = blockIdx.y * gx + blockIdx.x;
  int xcd = orig & 7, qq = nwg >> 3, rr = nwg & 7;
  int wg = (xcd < rr ? xcd * (qq + 1) : rr * (qq + 1) + (xcd - rr) * qq) + (orig >> 3);
  int row0 = (wg / gx) * 128, col0 = (wg % gx) * 128;

  int wm = (wave & 1) * 64, wn = (wave >> 1) * 64;
  int lr = lane & 15, quad = lane >> 4;

  f32x4 acc[4][4];
  #pragma unroll
  for (int i = 0; i < 4; ++i)
    #pragma unroll
    for (int j = 0; j < 4; ++j) acc[i][j] = (f32x4){0.f, 0.f, 0.f, 0.f};

  int r0 = tid >> 2, ko0 = (tid & 3) * 8;
  int r1 = (tid + 256) >> 2, ko1 = ((tid + 256) & 3) * 8;

  for (int k0 = 0; k0 < K; k0 += 32) {
    float4 av0 = *(const float4*)(A + (size_t)(row0 + r0) * lda + k0 + ko0);
    float4 av1 = *(const float4*)(A + (size_t)(row0 + r1) * lda + k0 + ko1);
    float4 bv0 = *(const float4*)(Bt + (size_t)(col0 + r0) * ldb + k0 + ko0);
    float4 bv1 = *(const float4*)(Bt + (size_t)(col0 + r1) * ldb + k0 + ko1);
    __syncthreads();
    *(float4*)&As[r0][ko0] = av0;
    *(float4*)&As[r1][ko1] = av1;
    *(float4*)&Bs[r0][ko0] = bv0;
    *(float4*)&Bs[r1][ko1] = bv1;
    __syncthreads();

    bf16x8 af[4], bfr[4];
    #pragma unroll
    for (int mi = 0; mi < 4; ++mi)
      af[mi] = *(const bf16x8*)&As[wm + mi * 16 + lr][quad * 8];
    #pragma unroll
    for (int ni = 0; ni < 4; ++ni)
      bfr[ni] = *(const bf16x8*)&Bs[wn + ni * 16 + lr][quad * 8];
    #pragma unroll
    for (int mi = 0; mi < 4; ++mi)
      #pragma unroll
      for (int ni = 0; ni < 4; ++ni)
        acc[mi][ni] = __builtin_amdgcn_mfma_f32_16x16x32_bf16(
            af[mi], bfr[ni], acc[mi][ni], 0, 0, 0);
  }

  // Epilogue. C/D layout: col = lane&15, row = quad*4 + reg.
  if (MODE == 1) {
    unsigned char* C = (unsigned char*)Cp;
    #pragma unroll
    for (int mi = 0; mi < 4; ++mi)
      #pragma unroll
      for (int ni = 0; ni < 4; ++ni) {
        int c = col0 + wn + ni * 16 + lr;
        float cb = (e3bias && c >= 200 && c < 400) ? e3bias[c - 200] : 0.f;
        #pragma unroll
        for (int reg = 0; reg < 4; ++reg) {
          int r = row0 + wm + mi * 16 + quad * 4 + reg;
          float x = (acc[mi][ni][reg] + cb) * QSC;
          int qi = (int)rintf(x);
          qi = qi > 127 ? 127 : (qi < -127 ? -127 : qi);
          C[(size_t)r * ldc + c] = (unsigned char)(qi + 128);
        }
      }
  } else {
    float* C = (float*)Cp;
    #pragma unroll
    for (int mi = 0; mi < 4; ++mi)
      #pragma unroll
      for (int ni = 0; ni < 4; ++ni) {
        int c = col0 + wn + ni * 16 + lr;
        if (c < N) {
          float bn = bias_n[c];
          #pragma unroll
          for (int reg = 0; reg < 4; ++reg) {
            int r = row0 + wm + mi * 16 + quad * 4 + reg;
            C[(size_t)r * ldc + c] = acc[mi][ni][reg] + bias_m[r] * bn;
          }
        }
      }
  }
}

// ---------------------------------------------------------------------------
// Scores, TITLE-per-wave, ROLLING-WINDOW over tokens, biased-uint8 E3.
// (unchanged from R4-passing version)
// ---------------------------------------------------------------------------
__global__ __launch_bounds__(256) void scores_kernel(
    const int* __restrict__ tok, const unsigned char* __restrict__ E3,
    const float* __restrict__ q2s, const float* __restrict__ qsum,
    float* __restrict__ expa) {
  __shared__ float qs[AD];
  __shared__ __align__(16) float red[4][NW][36];   // stride 36 floats = 144B (16B aligned)
  int tid = threadIdx.x;
  if (tid < AD) qs[tid] = q2s[tid];
  __syncthreads();
  int wave = tid >> 6, lane = tid & 63;
  int b = blockIdx.x * 4 + wave;
  int tk = tok[b * NW + ((lane < NW) ? lane : 0)];
  int d0 = (lane < 50) ? lane * 4 : 0;
  float4 qv = make_float4(0.f, 0.f, 0.f, 0.f);
  if (lane < 50) qv = *(const float4*)&qs[d0];   // lanes >=50 contribute 0
  float s01 = qv.x + qv.y, s23 = qv.z + qv.w;
  float Qsum = qsum[0];
  float* myred = &red[wave][0][lane >> 1];       // word stride = 36 floats

  // Prefetch row tok[0]: three 4B segment loads off one base.
  int t0r = __shfl(tk, 0, 64);
  const unsigned char* r0p = E3 + (size_t)(unsigned)t0r * E3_LDB + d0;
  unsigned int a0 = *(const unsigned int*)(r0p);          // seg0 -> s[1]
  unsigned int a1 = *(const unsigned int*)(r0p + 200);    // seg1 -> s[0]
  unsigned int a2 = *(const unsigned int*)(r0p + 400);    // seg2 -> s[-1] (dropped)

  // fp32 window of biased bytes; virtual seg0(tok[-1]) = bias 128.
  float P0 = 0.f, P1 = 0.f, P2 = 0.f, P3 = 0.f;
  float Q0 = 128.f, Q1 = 128.f, Q2 = 128.f, Q3 = 128.f;

  #pragma unroll
  for (int m = 0; m < NW; ++m) {
    unsigned int u0 = a0, u1 = a1, u2 = a2;
    if (m + 1 < NW) {   // prefetch next token's row (independent of below)
      int tn = __shfl(tk, m + 1, 64);
      const unsigned char* rp = E3 + (size_t)(unsigned)tn * E3_LDB + d0;
      a0 = *(const unsigned int*)(rp);
      a1 = *(const unsigned int*)(rp + 200);
      a2 = *(const unsigned int*)(rp + 400);
    }
    if (m > 0) {
      // complete s[m-1] with seg2 of current row; sigmoid; pair-park.
      float e0 = fexp2(fmaf(P0 + UBF(u2, 0), QDEC, QB3));
      float e1 = fexp2(fmaf(P1 + UBF(u2, 1), QDEC, QB3));
      float e2 = fexp2(fmaf(P2 + UBF(u2, 2), QDEC, QB3));
      float e3 = fexp2(fmaf(P3 + UBF(u2, 3), QDEC, QB3));
      float n01 = fmaf(qv.x, e1, s01); n01 = fmaf(qv.y, e0, n01);
      float n23 = fmaf(qv.z, e3, s23); n23 = fmaf(qv.w, e2, n23);
      float d01 = fmaf(e0, e1, (e0 + e1) + 1.0f);
      float d23 = fmaf(e2, e3, (e2 + e3) + 1.0f);
      float acc = n01 * __builtin_amdgcn_rcpf(d01);
      acc = fmaf(n23, __builtin_amdgcn_rcpf(d23), acc);
      acc += __shfl_xor(acc, 1, 64);          // lanes 2k,2k+1 now equal
      myred[(m - 1) * 36] = acc;              // benign same-value dual write
    }
    // advance window: P' = Q + seg1(tok[m]); Q' = seg0(tok[m])
    P0 = Q0 + UBF(u1, 0); P1 = Q1 + UBF(u1, 1);
    P2 = Q2 + UBF(u1, 2); P3 = Q3 + UBF(u1, 3);
    Q0 = UBF(u0, 0); Q1 = UBF(u0, 1);
    Q2 = UBF(u0, 2); Q3 = UBF(u0, 3);
  }
  { // epilogue: s[29] complete; missing seg2 -> bias 128
    float e0 = fexp2(fmaf(P0 + 128.f, QDEC, QB3));
    float e1 = fexp2(fmaf(P1 + 128.f, QDEC, QB3));
    float e2 = fexp2(fmaf(P2 + 128.f, QDEC, QB3));
    float e3 = fexp2(fmaf(P3 + 128.f, QDEC, QB3));
    float n01 = fmaf(qv.x, e1, s01); n01 = fmaf(qv.y, e0, n01);
    float n23 = fmaf(qv.z, e3, s23); n23 = fmaf(qv.w, e2, n23);
    float d01 = fmaf(e0, e1, (e0 + e1) + 1.0f);
    float d23 = fmaf(e2, e3, (e2 + e3) + 1.0f);
    float acc = n01 * __builtin_amdgcn_rcpf(d01);
    acc = fmaf(n23, __builtin_amdgcn_rcpf(d23), acc);
    acc += __shfl_xor(acc, 1, 64);
    myred[(NW - 1) * 36] = acc;
  }
  __syncthreads();
  // Transpose-reduce: word n's 32 partials; lane n sums j=0..15, lane n+32
  // sums j=16..31; xor-32 combines. Lanes with n>=30 are dummies.
  int n = lane & 31; if (n >= NW) n = 0;
  int half = lane >> 5;
  const float4* rp4 = (const float4*)&red[wave][n][half * 16];
  float4 s4 = rp4[0];
  #pragma unroll
  for (int j = 1; j < 4; ++j) {
    float4 vv = rp4[j];
    s4.x += vv.x; s4.y += vv.y; s4.z += vv.z; s4.w += vv.w;
  }
  float tot = (s4.x + s4.y) + (s4.z + s4.w);
  tot += __shfl_xor(tot, 32, 64);
  // |score| <= sum|q| ~ 16 -> exp safe in fp32; softmax needs no max-shift.
  float e = __expf(Qsum + tot);
  if (lane < NW) expa[(size_t)b * EXPA_LD + lane] = e;
}

// ---------------------------------------------------------------------------
// Softmax-over-batch denominators, stage 1: 128 blocks x 256 titles each.
// part[n][blk] = sum over block's titles of expa[b][n].
// ---------------------------------------------------------------------------
__global__ __launch_bounds__(256) void softmax_part(const float* __restrict__ expa,
                                                    float* __restrict__ part) {
  __shared__ float P[256][33];
  int tid = threadIdx.x;
  const float* row = expa + (size_t)(blockIdx.x * 256 + tid) * EXPA_LD;
  #pragma unroll
  for (int j = 0; j < 7; ++j) {
    float4 vv = *(const float4*)(row + j * 4);
    P[tid][j * 4] = vv.x; P[tid][j * 4 + 1] = vv.y;
    P[tid][j * 4 + 2] = vv.z; P[tid][j * 4 + 3] = vv.w;
  }
  P[tid][28] = row[28]; P[tid][29] = row[29];
  __syncthreads();
  int wave = tid >> 6, lane = tid & 63;
  for (int n = wave * 8; n < wave * 8 + 8 && n < NW; ++n) {
    float s = P[lane * 4][n] + P[lane * 4 + 1][n] + P[lane * 4 + 2][n] + P[lane * 4 + 3][n];
    #pragma unroll
    for (int off = 32; off > 0; off >>= 1) s += __shfl_down(s, off, 64);
    if (lane == 0) part[n * 128 + blockIdx.x] = s;
  }
}

// Stage 2: rinv[n] = 1 / sum_blk part[n][blk]
__global__ void softmax_fin(const float* __restrict__ part, float* __restrict__ rinv) {
  int n = blockIdx.x;          // 30
  int lane = threadIdx.x;      // 64
  float s = part[n * 128 + lane] + part[n * 128 + 64 + lane];
  #pragma unroll
  for (int off = 32; off > 0; off >>= 1) s += __shfl_down(s, off, 64);
  if (lane == 0) rinv[n] = 1.0f / s;
}

// ---------------------------------------------------------------------------
// U[b, k*300+i] = sum_m alpha[b, m-k+1] * emb[tok[b,m], i]  -> bf16, stride 928
// Salpha[b] = sum_n alpha[b,n].  alpha = expa * rinv.
// PREFETCH-ALL-30: issue all 30 gather loads back-to-back into registers
// (30-deep MLP, one vmcnt drain), preload 30 broadcast alphas to registers,
// then a pure-FMA accumulate loop. R4's VGPR=16 profile showed only ~2
// loads in flight -> latency-underlap was the bottleneck.
// ---------------------------------------------------------------------------
__global__ __launch_bounds__(192) void build_U(
    const int* __restrict__ tok, const unsigned short* __restrict__ embb,
    const float* __restrict__ expa, const float* __restrict__ rinv,
    unsigned short* __restrict__ U, float* __restrict__ Salpha) {
  int b = blockIdx.x;
  int tid = threadIdx.x;
  __shared__ float alpha[NW];
  __shared__ int ltok[NW];
  if (tid < NW) {
    ltok[tid] = tok[b * NW + tid];
    alpha[tid] = expa[(size_t)b * EXPA_LD + tid] * rinv[tid];
  }
  __syncthreads();
  if (tid == 0) {
    float s = 0.f;
    #pragma unroll
    for (int n = 0; n < NW; ++n) s += alpha[n];
    Salpha[b] = s;
  }
  unsigned short* Ub = U + (size_t)b * U_LD;
  if (tid < 150) {
    // Issue all 30 gathers (independent, fully unrolled -> 30 loads in flight)
    unsigned int uv[NW];
    #pragma unroll
    for (int m = 0; m < NW; ++m)
      uv[m] = *(const unsigned int*)(embb + (size_t)ltok[m] * EMB_LD + 2 * tid);
    // Broadcast alphas to registers (uniform ds_read, no conflicts)
    float al[NW];
    #pragma unroll
    for (int m = 0; m < NW; ++m) al[m] = alpha[m];

    float a0 = 0.f, a1 = 0.f, a2 = 0.f;   // col x = 2*tid
    float b0 = 0.f, b1 = 0.f, b2 = 0.f;   // col y = 2*tid+1
    #pragma unroll
    for (int m = 0; m < NW; ++m) {
      float w0 = (m + 1 < NW) ? al[m + 1] : 0.f;
      float w1 = al[m];
      float w2 = (m >= 1) ? al[m - 1] : 0.f;
      float x = blo(uv[m]), y = bhi(uv[m]);
      a0 = fmaf(w0, x, a0); b0 = fmaf(w0, y, b0);
      a1 = fmaf(w1, x, a1); b1 = fmaf(w1, y, b1);
      a2 = fmaf(w2, x, a2); b2 = fmaf(w2, y, b2);
    }
    *(unsigned int*)(Ub + 2 * tid)       = pack2bf(a0, b0);
    *(unsigned int*)(Ub + 300 + 2 * tid) = pack2bf(a1, b1);
    *(unsigned int*)(Ub + 600 + 2 * tid) = pack2bf(a2, b2);
  } else if (tid < 164) {
    *(unsigned int*)(Ub + 900 + 2 * (tid - 150)) = 0u;   // zero pad 900..927
  }
}

// ---------------------------------------------------------------------------
extern "C" void kernel_launch(void* const* d_in, const int* in_sizes, int n_in,
                              void* d_out, int out_size, void* d_ws, size_t ws_size,
                              hipStream_t stream) {
  const int*   tok    = (const int*)d_in[0];
  const float* emb    = (const float*)d_in[1];
  const float* conv_w = (const float*)d_in[2];
  const float* conv_b = (const float*)d_in[3];
  const float* v      = (const float*)d_in[4];
  const float* vb     = (const float*)d_in[5];
  const float* q      = (const float*)d_in[6];
  float* out = (float*)d_out;

  // Workspace layout (byte offsets). Total ~87.8 MB.
  char* wb = (char*)d_ws;
  float* bias2           = (float*)(wb + 0);          // 200 f32
  float* rinv            = (float*)(wb + 4096);       // 30 f32
  float* part            = (float*)(wb + 8192);       // 30*128 f32 -> 23552
  float* q2s             = (float*)(wb + 23552);      // 200 f32
  float* qsum            = (float*)(wb + 24448);      // 1 f32
  float* Salpha          = (float*)(wb + 24576);      // 32768 f32 -> 155648
  float* expa            = (float*)(wb + 155648);     // 32768*32 f32 -> 4349952
  unsigned short* embb   = (unsigned short*)(wb + 5070848);   // 20.48MB -> 25550848
  unsigned short* MtT    = (unsigned short*)(wb + 25550848);  // 409600 -> 25960448
  unsigned short* WcT    = (unsigned short*)(wb + 25960448);  // 950272 -> 26910720
  unsigned short* big    = (unsigned short*)(wb + 26910720);  // E3 u8 (20.5MB) / U (60.8MB)
  unsigned char* E3 = (unsigned char*)big;
  unsigned short* U = big;   // E3 dead after scores_kernel

  // 1. Prep
  hipLaunchKernelGGL(prep_MtT_bias, dim3(642), dim3(320), 0, stream,
                     conv_w, conv_b, v, vb, q, MtT, bias2, q2s, qsum);
  hipLaunchKernelGGL(prep_WcT, dim3(WCT_ROWS), dim3(256), 0, stream, conv_w, WcT);
  hipLaunchKernelGGL(prep_emb_bf16, dim3((VOCAB * EMB_LD) / 256), dim3(256), 0, stream,
                     emb, embb);
  // 2. E3[32000,640]u8 = quant(embb @ MtT^T)+128, bias2 folded into cols [200,400)
  hipLaunchKernelGGL((gemm_mfma<1>), dim3(E3_LDB / 128, VOCAB / 128), dim3(256), 0, stream,
                     embb, EMB_LD, MtT, EMB_LD, (void*)E3, E3_LDB, E3_LDB, EMB_LD,
                     (const float*)nullptr, (const float*)nullptr, bias2);
  // 3. exp(scores) -> expa[b][n]  (rolling-window uint8 gather, LDS reduce)
  hipLaunchKernelGGL(scores_kernel, dim3(BT / 4), dim3(256), 0, stream,
                     tok, E3, q2s, qsum, expa);
  // 4. Softmax denominators (2-stage, deterministic)
  hipLaunchKernelGGL(softmax_part, dim3(128), dim3(256), 0, stream, expa, part);
  hipLaunchKernelGGL(softmax_fin, dim3(NW), dim3(64), 0, stream, part, rinv);
  // 5. U[32768,928]bf16 + Salpha
  hipLaunchKernelGGL(build_U, dim3(BT), dim3(192), 0, stream,
                     tok, embb, expa, rinv, U, Salpha);
  // 6. out[32768,400]f32 = U @ WcT^T + Salpha ⊗ conv_b
  hipLaunchKernelGGL((gemm_mfma<0>), dim3(WCT_ROWS / 128, BT / 128), dim3(256), 0, stream,
                     U, U_LD, WcT, U_LD, (void*)out, CH, CH, U_LD,
                     Salpha, conv_b, (const float*)nullptr);
}